// Round 7
// baseline (313.387 us; speedup 1.0000x reference)
//
#include <hip/hip_runtime.h>
#include <hip/hip_bf16.h>

// Problem constants (fixed by the reference)
constexpr int BATCH  = 32;
constexpr int TIME   = 1024;
constexpr int IN_DIM = 512;
constexpr int HIDDEN = 512;

constexpr int GM = BATCH * TIME;   // 32768  (GEMM M)
constexpr int GN = HIDDEN;         // 512    (GEMM N)
constexpr int GK = IN_DIM;         // 512    (GEMM K)

// s_waitcnt imm fields: vmcnt[3:0]=bits0-3, expcnt=bits4-6, lgkmcnt=bits8-11,
// vmcnt[5:4]=bits14-15
#define WAITCNT_LGKMCNT(n) (0xF | (0x7 << 4) | (((n) & 0xF) << 8) | (0x3 << 14))
#define COMPILER_FENCE() asm volatile("" ::: "memory")

// ---------------- Phase 1: fp32 SGEMM with bias ----------------
// 128x128x16, 256 threads, 8x8 microtile, BOTH operands via LDS.
// Measured best across R1-R6 (203us, VALUBusy 68%). Structural analysis:
// LDS-read floor = 8.4M ds_read_b128 x 12cyc / 256CU = 164us > FMA 109us;
// at 203us we're ~83% of perfect pipe overlap -> near plateau for this
// shape. bytes/FMA is fixed at 1.0 for 8x8 (both operands via LDS), bigger
// microtile = VGPR cliff (R3), B-from-global = L2-latency stall (R5).
// KEEP AS-IS. VGPR discipline: plain __launch_bounds__(256) (R2 lesson).
constexpr int BM = 128;
constexpr int BN = 128;
constexpr int BK = 16;
constexpr int LDAs = BM + 4;   // padded (2-way LDS alias only = free)
constexpr int LDBs = BN + 4;

__global__ __launch_bounds__(256) void sgemm_bias_kernel(
    const float* __restrict__ A,     // [GM, GK]
    const float* __restrict__ B,     // [GK, GN]
    const float* __restrict__ bias,  // [GN]
    float* __restrict__ C)           // [GM, GN]
{
    __shared__ __align__(16) float As[BK * LDAs];
    __shared__ __align__(16) float Bs[BK * LDBs];

    const int tid = threadIdx.x;           // 0..255
    const int bm  = blockIdx.x * BM;       // M-tile (256): same-A blocks are
    const int bn  = blockIdx.y * BN;       // 256 apart -> same XCD (L2 reuse)

    const int w    = tid >> 6;
    const int lane = tid & 63;
    const int row0 = (w >> 1) * 64 + (lane >> 3) * 8;
    const int col0 = (w & 1)  * 64 + (lane & 7)  * 8;

    const int ar0 = tid >> 2;              // A row for quad 0 (0..63), +64
    const int ac  = (tid & 3) << 2;        // A col within K-tile (0..12)
    const int br0 = tid >> 5;              // B row for quad 0 (0..7), +8
    const int bc  = (tid & 31) << 2;       // B col within N-tile (0..124)

    float acc[8][8];
    #pragma unroll
    for (int i = 0; i < 8; ++i)
        #pragma unroll
        for (int j = 0; j < 8; ++j) acc[i][j] = 0.0f;

    #pragma unroll 1
    for (int k0 = 0; k0 < GK; k0 += BK) {
        float4 va0 = *reinterpret_cast<const float4*>(A + (size_t)(bm + ar0) * GK + k0 + ac);
        float4 va1 = *reinterpret_cast<const float4*>(A + (size_t)(bm + ar0 + 64) * GK + k0 + ac);
        float4 vb0 = *reinterpret_cast<const float4*>(B + (size_t)(k0 + br0) * GN + bn + bc);
        float4 vb1 = *reinterpret_cast<const float4*>(B + (size_t)(k0 + br0 + 8) * GN + bn + bc);

        __syncthreads();   // previous tile's compute done before overwrite

        As[(ac + 0) * LDAs + ar0] = va0.x;
        As[(ac + 1) * LDAs + ar0] = va0.y;
        As[(ac + 2) * LDAs + ar0] = va0.z;
        As[(ac + 3) * LDAs + ar0] = va0.w;
        As[(ac + 0) * LDAs + ar0 + 64] = va1.x;
        As[(ac + 1) * LDAs + ar0 + 64] = va1.y;
        As[(ac + 2) * LDAs + ar0 + 64] = va1.z;
        As[(ac + 3) * LDAs + ar0 + 64] = va1.w;
        *reinterpret_cast<float4*>(&Bs[br0 * LDBs + bc]) = vb0;
        *reinterpret_cast<float4*>(&Bs[(br0 + 8) * LDBs + bc]) = vb1;

        __syncthreads();

        #pragma unroll
        for (int kk = 0; kk < BK; ++kk) {
            const float4 a0 = *reinterpret_cast<const float4*>(&As[kk * LDAs + row0]);
            const float4 a1 = *reinterpret_cast<const float4*>(&As[kk * LDAs + row0 + 4]);
            const float4 b0 = *reinterpret_cast<const float4*>(&Bs[kk * LDBs + col0]);
            const float4 b1 = *reinterpret_cast<const float4*>(&Bs[kk * LDBs + col0 + 4]);
            const float arr[8] = {a0.x, a0.y, a0.z, a0.w, a1.x, a1.y, a1.z, a1.w};
            const float brr[8] = {b0.x, b0.y, b0.z, b0.w, b1.x, b1.y, b1.z, b1.w};
            #pragma unroll
            for (int i = 0; i < 8; ++i)
                #pragma unroll
                for (int j = 0; j < 8; ++j)
                    acc[i][j] = fmaf(arr[i], brr[j], acc[i][j]);
        }
    }

    // ---- epilogue: add bias (separate fp32 add, like numpy), store ----
    #pragma unroll
    for (int i = 0; i < 8; ++i) {
        const size_t r = (size_t)(bm + row0 + i);
        #pragma unroll
        for (int j = 0; j < 8; j += 4) {
            float4 v;
            v.x = __fadd_rn(acc[i][j + 0], bias[bn + col0 + j + 0]);
            v.y = __fadd_rn(acc[i][j + 1], bias[bn + col0 + j + 1]);
            v.z = __fadd_rn(acc[i][j + 2], bias[bn + col0 + j + 2]);
            v.w = __fadd_rn(acc[i][j + 3], bias[bn + col0 + j + 3]);
            *reinterpret_cast<float4*>(&C[r * GN + bn + col0 + j]) = v;
        }
    }
}

// ---------------- Phase 2: LIF scan v5 — 3 producers + 1 consumer ----------
// R3-R6 scans all plateau ~100us at ONE streaming wave/CU (~5 GB/s/wave,
// ~4-5 KB effective in flight; the global_load_lds DMA path seems to cap
// outstanding per wave regardless of my vmcnt). v5: 4 waves/block; waves
// 0-2 are producers on the KNOWN-GOOD register-load + ds_write path (same
// as the GEMM's staging, which demonstrably pipelines), each owning chunks
// c%3==p with a depth-2 register pipeline (8 float4 loads in flight each).
// Wave 3 consumes. Flag ordering: ds_write -> s_waitcnt lgkmcnt(0) (LDS-only
// wait, ~30cyc, NOT a vmcnt drain) -> relaxed flag store.
constexpr int SH   = 64;               // h-columns per block
constexpr int SCH  = 16;               // timesteps per chunk
constexpr int NCHK = TIME / SCH;       // 64 chunks
constexpr int RT   = 256;              // ring capacity in t-slots (64 KB)
constexpr int RCH  = RT / SCH;         // 16 ring chunks

__global__ __launch_bounds__(256) void lif_scan_kernel(
    const float* __restrict__ I,   // [B, T, H]
    float* __restrict__ O)         // [B, T, H]
{
    __shared__ __align__(16) float ring[RT * SH];   // 64 KB
    __shared__ int prod_f[3];              // last chunk landed, per producer
    __shared__ int cons_c;                 // chunks consumed

    const int blk  = blockIdx.x;           // 0..255
    const int b    = blk >> 3;             // 8 blocks per batch row
    const int h0   = (blk & 7) * SH;
    const int wave = threadIdx.x >> 6;
    const int lane = threadIdx.x & 63;
    const size_t base0 = (size_t)b * TIME * HIDDEN + h0;

    if (threadIdx.x < 3) prod_f[threadIdx.x] = -1;
    if (threadIdx.x == 3) cons_c = 0;
    __syncthreads();

    if (wave < 3) {
        // ---------------- producer p: chunks c = p, p+3, p+6, ... ----------
        const int p = wave;
        // lane i covers t = c*16 + u*4 + i/16, h = h0 + (i%16)*4 .. +3 (16B)
        const float* g0 = I + base0 + (size_t)(lane >> 4) * HIDDEN + (lane & 15) * 4;

        float4 rr[2][4];
        auto loadc = [&](float4* r, int c) {
            #pragma unroll
            for (int u = 0; u < 4; ++u)
                r[u] = *reinterpret_cast<const float4*>(
                    g0 + (size_t)(c * SCH + u * 4) * HIDDEN);
        };

        loadc(rr[0], p);                   // prologue: own first chunk
        int q = 0;
        #pragma unroll 1
        for (int c = p; c < NCHK; c += 3) {
            const int cn = c + 3;
            // issue next chunk's loads first (stay in flight behind ds_write;
            // compiler waits only the older vmcnt group for rr[q])
            loadc(rr[q ^ 1], (cn < NCHK) ? cn : c);
            // backpressure: slot (c % RCH) must be consumed
            if (c >= RCH) {
                while (__hip_atomic_load(&cons_c, __ATOMIC_RELAXED,
                                         __HIP_MEMORY_SCOPE_WORKGROUP)
                       < c - RCH + 1) { }
                COMPILER_FENCE();
            }
            const int slot = (c & (RCH - 1)) * SCH;
            float* dst = &ring[(slot + (lane >> 4)) * SH + (lane & 15) * 4];
            #pragma unroll
            for (int u = 0; u < 4; ++u)
                *reinterpret_cast<float4*>(dst + u * 4 * SH) = rr[q][u];
            COMPILER_FENCE();
            __builtin_amdgcn_s_waitcnt(WAITCNT_LGKMCNT(0));  // LDS writes done
            COMPILER_FENCE();
            __hip_atomic_store(&prod_f[p], c, __ATOMIC_RELAXED,
                               __HIP_MEMORY_SCOPE_WORKGROUP);
            q ^= 1;
        }
    } else {
        // ---------------- consumer: 1 chain per lane ----------------
        // exp(-0.05), exp(-0.2) correctly rounded fp32 (match np.exp)
        const float am = 0.95122942450071400910f;
        const float as = 0.81873075307798185867f;
        float v = 0.0f, s = 0.0f;
        float* o0 = O + base0 + lane;

        #pragma unroll 1
        for (int c = 0; c < NCHK; ++c) {
            const int src = c % 3;
            while (__hip_atomic_load(&prod_f[src], __ATOMIC_RELAXED,
                                     __HIP_MEMORY_SCOPE_WORKGROUP) < c) { }
            COMPILER_FENCE();
            const int slot = (c & (RCH - 1)) * SCH;
            float ob[SCH];
            #pragma unroll
            for (int u = 0; u < SCH; ++u) {
                const float x = ring[(slot + u) * SH + lane];
                // separate mul/add roundings to match numpy (no FMA fusion)
                s = __fadd_rn(__fmul_rn(as, s), x);
                v = __fadd_rn(__fmul_rn(am, v), s);
                const float o = (v > 1.0f) ? 1.0f : 0.0f;
                v = __fsub_rn(v, o);
                ob[u] = o;
            }
            COMPILER_FENCE();   // ring values are in regs before publish
            __hip_atomic_store(&cons_c, c + 1, __ATOMIC_RELAXED,
                               __HIP_MEMORY_SCOPE_WORKGROUP);
            #pragma unroll
            for (int u = 0; u < SCH; ++u)
                o0[(size_t)(c * SCH + u) * HIDDEN] = ob[u];
        }
    }
}

extern "C" void kernel_launch(void* const* d_in, const int* in_sizes, int n_in,
                              void* d_out, int out_size, void* d_ws, size_t ws_size,
                              hipStream_t stream) {
    const float* spikes = (const float*)d_in[0];   // [32, 1024, 512]
    const float* W      = (const float*)d_in[1];   // [512, 512]
    const float* bias   = (const float*)d_in[2];   // [512]
    float* out  = (float*)d_out;                   // [32, 1024, 512]
    float* I_in = (float*)d_ws;                    // 64 MiB scratch

    dim3 g1(GM / BM, GN / BN);                     // (256, 4)
    sgemm_bias_kernel<<<g1, 256, 0, stream>>>(spikes, W, bias, I_in);

    lif_scan_kernel<<<BATCH * HIDDEN / SH, 256, 0, stream>>>(I_in, out);
}

// Round 8
// 313.044 us; speedup vs baseline: 1.0011x; 1.0011x over previous
//
#include <hip/hip_runtime.h>
#include <hip/hip_bf16.h>

// Problem constants (fixed by the reference)
constexpr int BATCH  = 32;
constexpr int TIME   = 1024;
constexpr int IN_DIM = 512;
constexpr int HIDDEN = 512;

constexpr int GM = BATCH * TIME;   // 32768  (GEMM M)
constexpr int GN = HIDDEN;         // 512    (GEMM N)
constexpr int GK = IN_DIM;         // 512    (GEMM K)

#define GLOBAL_AS __attribute__((address_space(1)))
#define LDS_AS    __attribute__((address_space(3)))

// s_waitcnt imm fields: vmcnt[3:0]=bits0-3, expcnt=bits4-6, lgkmcnt=bits8-11,
// vmcnt[5:4]=bits14-15
#define WAITCNT_VMCNT(n) (((n) & 15) | (((n) >> 4) << 14) | (0x7 << 4) | (0xF << 8))
#define COMPILER_FENCE() asm volatile("" ::: "memory")

// ---------------- Phase 1: fp32 SGEMM with bias ----------------
// 128x128x16, 256 threads, 8x8 microtile, BOTH operands via LDS. Best
// measured body (R6: 203us, VALUBusy 68%; LDS-read floor ~164us, FMA floor
// ~109us -> ~83% of perfect overlap). KEEP. Epilogue now writes I_in in
// SCAN-FRIENDLY layout [B, H/64, T, 64] so each scan block reads a fully
// CONTIGUOUS panel (kills the 256B@2KB strided stream that pinned every
// scan variant at ~1.2 TB/s -- suspected HBM channel imbalance).
constexpr int BM = 128;
constexpr int BN = 128;
constexpr int BK = 16;
constexpr int LDAs = BM + 4;   // padded (2-way LDS alias only = free)
constexpr int LDBs = BN + 4;

__global__ __launch_bounds__(256) void sgemm_bias_kernel(
    const float* __restrict__ A,     // [GM, GK]
    const float* __restrict__ B,     // [GK, GN]
    const float* __restrict__ bias,  // [GN]
    float* __restrict__ C)           // [B, H/64, T, 64] permuted I_in
{
    __shared__ __align__(16) float As[BK * LDAs];
    __shared__ __align__(16) float Bs[BK * LDBs];

    const int tid = threadIdx.x;           // 0..255
    const int bm  = blockIdx.x * BM;       // M-tile (256): same-A blocks are
    const int bn  = blockIdx.y * BN;       // 256 apart -> same XCD (L2 reuse)

    const int w    = tid >> 6;
    const int lane = tid & 63;
    const int row0 = (w >> 1) * 64 + (lane >> 3) * 8;
    const int col0 = (w & 1)  * 64 + (lane & 7)  * 8;

    const int ar0 = tid >> 2;              // A row for quad 0 (0..63), +64
    const int ac  = (tid & 3) << 2;        // A col within K-tile (0..12)
    const int br0 = tid >> 5;              // B row for quad 0 (0..7), +8
    const int bc  = (tid & 31) << 2;       // B col within N-tile (0..124)

    float acc[8][8];
    #pragma unroll
    for (int i = 0; i < 8; ++i)
        #pragma unroll
        for (int j = 0; j < 8; ++j) acc[i][j] = 0.0f;

    #pragma unroll 1
    for (int k0 = 0; k0 < GK; k0 += BK) {
        float4 va0 = *reinterpret_cast<const float4*>(A + (size_t)(bm + ar0) * GK + k0 + ac);
        float4 va1 = *reinterpret_cast<const float4*>(A + (size_t)(bm + ar0 + 64) * GK + k0 + ac);
        float4 vb0 = *reinterpret_cast<const float4*>(B + (size_t)(k0 + br0) * GN + bn + bc);
        float4 vb1 = *reinterpret_cast<const float4*>(B + (size_t)(k0 + br0 + 8) * GN + bn + bc);

        __syncthreads();   // previous tile's compute done before overwrite

        As[(ac + 0) * LDAs + ar0] = va0.x;
        As[(ac + 1) * LDAs + ar0] = va0.y;
        As[(ac + 2) * LDAs + ar0] = va0.z;
        As[(ac + 3) * LDAs + ar0] = va0.w;
        As[(ac + 0) * LDAs + ar0 + 64] = va1.x;
        As[(ac + 1) * LDAs + ar0 + 64] = va1.y;
        As[(ac + 2) * LDAs + ar0 + 64] = va1.z;
        As[(ac + 3) * LDAs + ar0 + 64] = va1.w;
        *reinterpret_cast<float4*>(&Bs[br0 * LDBs + bc]) = vb0;
        *reinterpret_cast<float4*>(&Bs[(br0 + 8) * LDBs + bc]) = vb1;

        __syncthreads();

        #pragma unroll
        for (int kk = 0; kk < BK; ++kk) {
            const float4 a0 = *reinterpret_cast<const float4*>(&As[kk * LDAs + row0]);
            const float4 a1 = *reinterpret_cast<const float4*>(&As[kk * LDAs + row0 + 4]);
            const float4 b0 = *reinterpret_cast<const float4*>(&Bs[kk * LDBs + col0]);
            const float4 b1 = *reinterpret_cast<const float4*>(&Bs[kk * LDBs + col0 + 4]);
            const float arr[8] = {a0.x, a0.y, a0.z, a0.w, a1.x, a1.y, a1.z, a1.w};
            const float brr[8] = {b0.x, b0.y, b0.z, b0.w, b1.x, b1.y, b1.z, b1.w};
            #pragma unroll
            for (int i = 0; i < 8; ++i)
                #pragma unroll
                for (int j = 0; j < 8; ++j)
                    acc[i][j] = fmaf(arr[i], brr[j], acc[i][j]);
        }
    }

    // ---- epilogue: bias add + store to [B, H/64, T, 64] ----
    const int b = (bm + row0) >> 10;       // whole 8-row microtile is in one b
    #pragma unroll
    for (int i = 0; i < 8; ++i) {
        const int t = (bm + row0 + i) & 1023;
        #pragma unroll
        for (int j = 0; j < 8; j += 4) {
            const int h  = bn + col0 + j;  // h%64 in 0..60 -> float4 intact
            const int hs = h >> 6;
            float4 v;
            v.x = __fadd_rn(acc[i][j + 0], bias[h + 0]);
            v.y = __fadd_rn(acc[i][j + 1], bias[h + 1]);
            v.z = __fadd_rn(acc[i][j + 2], bias[h + 2]);
            v.w = __fadd_rn(acc[i][j + 3], bias[h + 3]);
            *reinterpret_cast<float4*>(
                &C[(((size_t)(b * 8 + hs)) * TIME + t) * 64 + (h & 63)]) = v;
        }
    }
}

// ---------------- Phase 2: LIF scan v6 — contiguous-panel DMA ring --------
// I_in is [B, 8, T, 64]: block (b,hs) streams a fully CONTIGUOUS 256 KB
// panel. Producer wave: 4 KB chunk = 4 x width-16 DMA of 1 KB, sequential
// addresses; vmcnt(16) retirement. Consumer wave: 1 (s,v) chain per lane.
// Output writes stay [B,T,H] (fixed layout).
constexpr int SCH  = 16;               // timesteps per chunk
constexpr int NCHK = TIME / SCH;       // 64 chunks
constexpr int RT   = 256;              // ring capacity in t-slots (64 KB)
constexpr int RCH  = RT / SCH;         // 16 ring chunks

__global__ __launch_bounds__(128) void lif_scan_kernel(
    const float* __restrict__ I2,  // [B, 8, T, 64]
    float* __restrict__ O)         // [B, T, H]
{
    __shared__ __align__(16) float ring[RT * 64];   // 64 KB
    __shared__ int prod_c;                 // chunks fully landed in LDS
    __shared__ int cons_c;                 // chunks consumed

    const int blk  = blockIdx.x;           // 0..255  (= b*8 + hs)
    const int b    = blk >> 3;
    const int hs   = blk & 7;
    const int wave = threadIdx.x >> 6;
    const int lane = threadIdx.x & 63;

    const float* In = I2 + (size_t)blk * TIME * 64;          // contiguous panel
    float*       On = O + (size_t)b * TIME * HIDDEN + hs * 64;

    if (threadIdx.x == 0) { prod_c = 0; cons_c = 0; }
    __syncthreads();

    if (wave == 0) {
        // ---------------- producer: sequential 1 KB DMAs ----------------
        const float* g0 = In + lane * 4;   // 16 B per lane, contiguous 1 KB
        #pragma unroll 1
        for (int c = 0; c < NCHK; ++c) {
            if (c >= RCH) {   // ring slot reuse: chunk c-RCH must be consumed
                while (__hip_atomic_load(&cons_c, __ATOMIC_RELAXED,
                                         __HIP_MEMORY_SCOPE_WORKGROUP)
                       < c - RCH + 1) { }
                COMPILER_FENCE();
            }
            const int slot = (c & (RCH - 1)) * SCH;
            #pragma unroll
            for (int u = 0; u < 4; ++u) {   // 4 x 1KB, fully sequential
                __builtin_amdgcn_global_load_lds(
                    (GLOBAL_AS const void*)(g0 + (size_t)c * SCH * 64 + u * 256),
                    (LDS_AS void*)&ring[slot * 64 + u * 256], 16, 0, 0);
            }
            COMPILER_FENCE();
            // allow 16 outstanding = chunks c..c-3  =>  <= c-4 have landed
            __builtin_amdgcn_s_waitcnt(WAITCNT_VMCNT(16));
            COMPILER_FENCE();
            if (c >= 4)
                __hip_atomic_store(&prod_c, c - 3, __ATOMIC_RELAXED,
                                   __HIP_MEMORY_SCOPE_WORKGROUP);
        }
        COMPILER_FENCE();
        __builtin_amdgcn_s_waitcnt(WAITCNT_VMCNT(0));
        COMPILER_FENCE();
        __hip_atomic_store(&prod_c, NCHK, __ATOMIC_RELAXED,
                           __HIP_MEMORY_SCOPE_WORKGROUP);
    } else {
        // ---------------- consumer: 1 chain per lane ----------------
        // exp(-0.05), exp(-0.2) correctly rounded fp32 (match np.exp)
        const float am = 0.95122942450071400910f;
        const float as = 0.81873075307798185867f;
        float v = 0.0f, s = 0.0f;
        float* o0 = On + lane;

        #pragma unroll 1
        for (int c = 0; c < NCHK; ++c) {
            while (__hip_atomic_load(&prod_c, __ATOMIC_RELAXED,
                                     __HIP_MEMORY_SCOPE_WORKGROUP) < c + 1) { }
            COMPILER_FENCE();
            const int slot = (c & (RCH - 1)) * SCH;
            float ob[SCH];
            #pragma unroll
            for (int u = 0; u < SCH; ++u) {
                const float x = ring[(slot + u) * 64 + lane];
                // separate mul/add roundings to match numpy (no FMA fusion)
                s = __fadd_rn(__fmul_rn(as, s), x);
                v = __fadd_rn(__fmul_rn(am, v), s);
                const float o = (v > 1.0f) ? 1.0f : 0.0f;
                v = __fsub_rn(v, o);
                ob[u] = o;
            }
            COMPILER_FENCE();   // ring values are in regs before publish
            __hip_atomic_store(&cons_c, c + 1, __ATOMIC_RELAXED,
                               __HIP_MEMORY_SCOPE_WORKGROUP);
            #pragma unroll
            for (int u = 0; u < SCH; ++u)
                o0[(size_t)(c * SCH + u) * HIDDEN] = ob[u];
        }
    }
}

extern "C" void kernel_launch(void* const* d_in, const int* in_sizes, int n_in,
                              void* d_out, int out_size, void* d_ws, size_t ws_size,
                              hipStream_t stream) {
    const float* spikes = (const float*)d_in[0];   // [32, 1024, 512]
    const float* W      = (const float*)d_in[1];   // [512, 512]
    const float* bias   = (const float*)d_in[2];   // [512]
    float* out  = (float*)d_out;                   // [32, 1024, 512]
    float* I_in = (float*)d_ws;                    // 64 MiB scratch, [B,8,T,64]

    dim3 g1(GM / BM, GN / BN);                     // (256, 4)
    sgemm_bias_kernel<<<g1, 256, 0, stream>>>(spikes, W, bias, I_in);

    lif_scan_kernel<<<256, 128, 0, stream>>>(I_in, out);
}